// Round 6
// baseline (438.541 us; speedup 1.0000x reference)
//
#include <hip/hip_runtime.h>
#include <hip/hip_bf16.h>
#include <math.h>

#define B_  4
#define S_  2048
#define D_  768
#define H_  12
#define HD_ 64
#define DF_ 3072
#define BS_ (B_*S_)

// 0.125 (hd^-0.5) * log2(e): folded into Q projection so softmax runs in exp2 domain
#define QSCALE 0.18033688011112042f

typedef __attribute__((ext_vector_type(8)))  short short8;
typedef __attribute__((ext_vector_type(4)))  float f32x4;
typedef __attribute__((ext_vector_type(16))) float f32x16;
typedef __attribute__((ext_vector_type(4)))  int  int4v;

__device__ __forceinline__ unsigned short f2b(float f){
    unsigned int x = __float_as_uint(f);
    return (unsigned short)((x + 0x7fffu + ((x >> 16) & 1u)) >> 16);   // RNE
}
__device__ __forceinline__ float b2f(unsigned short u){
    return __uint_as_float(((unsigned int)u) << 16);
}

typedef __attribute__((address_space(1))) void gvoid_t;
typedef __attribute__((address_space(3))) void lvoid_t;
__device__ __forceinline__ void gload_lds16(const unsigned short* g, unsigned short* l){
    __builtin_amdgcn_global_load_lds((gvoid_t*)g, (lvoid_t*)l, 16, 0, 0);
}

// ---------------------------------------------------------------- merged prep
// sections: 6144 cvt-x (float4) | 4*576 DxD transposes | 2304 W1 | 2304 W2 | 9 bias
__global__ __launch_bounds__(256) void prep_kernel(
    const float* __restrict__ x,
    const float* __restrict__ Wq, const float* __restrict__ Wk,
    const float* __restrict__ Wv, const float* __restrict__ Wo,
    const float* __restrict__ W1, const float* __restrict__ W2,
    const float* __restrict__ bq, const float* __restrict__ bk, const float* __restrict__ bv,
    unsigned short* __restrict__ xb, unsigned short* __restrict__ wqkvT,
    unsigned short* __restrict__ woT, unsigned short* __restrict__ w1T,
    unsigned short* __restrict__ w2T, float* __restrict__ bqkv)
{
    const int NCVT = (BS_*D_)/1024;        // 6144
    int bid = blockIdx.x;
    if (bid < NCVT){
        int i = (bid*256 + threadIdx.x)*4;
        float4 v = *(const float4*)(x + i);
        ushort4 o4 = { f2b(v.x), f2b(v.y), f2b(v.z), f2b(v.w) };
        *(ushort4*)(xb + i) = o4;
        return;
    }
    bid -= NCVT;
    __shared__ float t[32][33];
    const float* src; unsigned short* dst; int K, N, bx, by;
    if (bid < 4*576){
        int wsel = bid / 576, tt = bid % 576;
        bx = tt % 24; by = tt / 24; K = D_; N = D_;
        src = (wsel==0)?Wq:(wsel==1)?Wk:(wsel==2)?Wv:Wo;
        dst = (wsel<3) ? (wqkvT + (size_t)wsel*D_*D_) : woT;
    } else if (bid < 4*576 + 2304){
        int tt = bid - 4*576; bx = tt % 96; by = tt / 96; K = D_; N = DF_; src = W1; dst = w1T;
    } else if (bid < 4*576 + 2*2304){
        int tt = bid - 4*576 - 2304; bx = tt % 24; by = tt / 24; K = DF_; N = D_; src = W2; dst = w2T;
    } else {
        int i = (bid - (4*576 + 2*2304))*256 + threadIdx.x;
        if (i < 3*D_) bqkv[i] = (i < D_) ? bq[i] : (i < 2*D_) ? bk[i-D_] : bv[i-2*D_];
        return;
    }
    int tx = threadIdx.x & 31, ty = threadIdx.x >> 5;
    #pragma unroll
    for (int i = 0; i < 4; ++i)
        t[ty + i*8][tx] = src[(size_t)(by*32 + ty + i*8) * N + bx*32 + tx];
    __syncthreads();
    #pragma unroll
    for (int i = 0; i < 4; ++i)
        dst[(size_t)(bx*32 + ty + i*8) * K + by*32 + tx] = f2b(t[tx][ty + i*8]);
}

// ---------------------------------------------------------------- GEMM (BK=64, 32x32x16 MFMA)
// C[M,N] = A[M,K] @ Bt[N,K]^T + bias.  BM=BN=128, 4 waves 2x2 of 64x64 (each 2x2 of 32x32).
// A-frag: m=lane&31, k=(lane>>5)*8+j.  C/D: col=lane&31, row=(r&3)+8*(r>>2)+4*(lane>>5).
// Staging via global_load_lds w/ XOR chunk swizzle. act: 0 none, 1 tanh-GELU, 2 QKV-mode.
// split-K via blockIdx.z (klen per z).
__global__ __launch_bounds__(256, 3) void gemm_tn(
    const unsigned short* __restrict__ A,
    const unsigned short* __restrict__ Bt,
    const float* __restrict__ bias,
    float* __restrict__ Cf,
    unsigned short* __restrict__ Cb,
    unsigned short* __restrict__ vtg,
    int M, int N, int K, int klen, int act)
{
    __shared__ __align__(16) unsigned short As[128*64];
    __shared__ __align__(16) unsigned short Bs[128*64];

    const int tid  = threadIdx.x;
    const int bm   = blockIdx.y, bn = blockIdx.x, bz = blockIdx.z;
    const int w    = tid >> 6, lane = tid & 63;
    const int l32  = lane & 31, hh2 = lane >> 5;
    const int wm   = (w >> 1) * 64, wn = (w & 1) * 64;
    const int kbeg = bz * klen;

    const unsigned short* Abase = A  + (size_t)bm * 128 * K;
    const unsigned short* Bbase = Bt + (size_t)bn * 128 * K;

    f32x16 acc[2][2] = {};

    for (int kt = kbeg; kt < kbeg + klen; kt += 64){
        #pragma unroll
        for (int c0 = 0; c0 < 4; ++c0){
            int c = tid + c0 * 256;                 // 1024 chunks of 16B per matrix
            int row = c >> 3, q = c & 7;
            int sw = (q ^ row) & 7;                 // chunk swizzle
            gload_lds16(Abase + (size_t)row * K + kt + sw*8, As + c*8);
            gload_lds16(Bbase + (size_t)row * K + kt + sw*8, Bs + c*8);
        }
        __syncthreads();

        #pragma unroll
        for (int s = 0; s < 4; ++s){                // 4 k-steps of 16
            short8 af[2], bf[2];
            int cidx = s*2 + hh2;
            #pragma unroll
            for (int mi = 0; mi < 2; ++mi)
                af[mi] = *(const short8*)&As[(wm + mi*32 + l32)*64 + ((cidx ^ l32) & 7)*8];
            #pragma unroll
            for (int ni = 0; ni < 2; ++ni)
                bf[ni] = *(const short8*)&Bs[(wn + ni*32 + l32)*64 + ((cidx ^ l32) & 7)*8];
            #pragma unroll
            for (int mi = 0; mi < 2; ++mi)
                #pragma unroll
                for (int ni = 0; ni < 2; ++ni)
                    acc[mi][ni] = __builtin_amdgcn_mfma_f32_32x32x16_bf16(af[mi], bf[ni], acc[mi][ni], 0, 0, 0);
        }
        __syncthreads();
    }

    if (act == 2 && bn >= 12){
        // V cols: vtg[(b*H+h)*64 + d][s] with within-32 slot permutation
        // slot(k) = ((k>>2)&3)*8 + ((k>>4)&1)*4 + (k&3)
        #pragma unroll
        for (int mi = 0; mi < 2; ++mi){
            #pragma unroll
            for (int g = 0; g < 4; ++g){
                int rowbase = bm*128 + wm + mi*32 + 8*g + 4*hh2;
                int bidx = rowbase >> 11, s0 = rowbase & 2047;
                int sp = (s0 & ~31) | (((s0 >> 2) & 3) << 3) | (((s0 >> 4) & 1) << 2);
                #pragma unroll
                for (int ni = 0; ni < 2; ++ni){
                    int col  = bn*128 + wn + ni*32 + l32;
                    int hcol = col - 2*D_;
                    int hv   = hcol >> 6, dd = hcol & 63;
                    float bia = bias ? bias[col] : 0.f;
                    unsigned long long pk = 0;
                    #pragma unroll
                    for (int rr = 0; rr < 4; ++rr)
                        pk |= (unsigned long long)f2b(acc[mi][ni][4*g + rr] + bia) << (16*rr);
                    *(unsigned long long*)(vtg + (((size_t)bidx*H_ + hv)*64 + dd)*2048 + sp) = pk;
                }
            }
        }
        return;
    }

    float* Cfz = Cf ? (Cf + (size_t)bz * M * N) : nullptr;
    const bool addb = (bias != nullptr) && (bz == 0);
    #pragma unroll
    for (int mi = 0; mi < 2; ++mi){
        #pragma unroll
        for (int ni = 0; ni < 2; ++ni){
            int col = bn*128 + wn + ni*32 + l32;
            float bia = addb ? bias[col] : 0.f;
            #pragma unroll
            for (int r = 0; r < 16; ++r){
                int row = bm*128 + wm + mi*32 + (r & 3) + 8*(r >> 2) + 4*hh2;
                float v = acc[mi][ni][r] + bia;
                if (act == 1){
                    // tanh-GELU (max abs err ~3e-4, well within tolerance)
                    float u = v * (0.7978845608028654f + 0.0356774081f * v * v);
                    float e = __builtin_amdgcn_exp2f(u * 2.885390081777927f);  // e^(2u)
                    v = 0.5f * v * (1.f + (1.f - 2.f / (e + 1.f)));
                } else if (act == 2 && col < D_) v *= QSCALE;
                size_t idx = (size_t)row * N + col;
                if (Cfz) Cfz[idx] = v;
                if (Cb) Cb[idx] = f2b(v);
            }
        }
    }
}

// ---------------------------------------------------------------- attention
// S^T = K Q^T; P^T's C-layout regs ARE the PV A-fragment under key-permutation pi;
// V^T stored globally with pi pre-applied. No-max softmax (p = exp2(s) directly).
// 512 threads (8 waves x 16 q = 128 q/block), 128-key tiles, fused per-32-key
// granule S->exp->PV. ctx written via LDS repack for 16B coalesced stores.
__global__ __launch_bounds__(512, 6) void attn_kernel(
    const unsigned short* __restrict__ qkv,
    const unsigned short* __restrict__ vtg,
    const int* __restrict__ mask,
    unsigned short* __restrict__ ctx)
{
    __shared__ __align__(16) unsigned short Kl[128*64];   // [key][dchunk ^ (key&7)]
    __shared__ __align__(16) unsigned short Vt[64*128];   // [d][slotchunk ^ (d&15)]

    const int tid = threadIdx.x;
    const int bid = blockIdx.x;                  // 768 = 48 heads * 16 qb
    const int hid = bid % 48;                    // same head -> same XCD (bid%8 fixed)
    const int qb  = bid / 48;
    const int h   = hid % H_;
    const int b   = hid / H_;
    const int w   = tid >> 6, lane = tid & 63;
    const int l16 = lane & 15, quad = lane >> 4;
    const int q0  = qb * 128 + w * 16;
    const size_t base = (size_t)b * S_;
    const int hoff = h * HD_;

    // Q as B-frag: n=q=lane&15, k-slot (quad,j) -> d = kc*32+quad*8+j
    short8 qf[2];
    #pragma unroll
    for (int kc = 0; kc < 2; ++kc)
        qf[kc] = *(const short8*)(qkv + (base + q0 + l16)*2304 + hoff + kc*32 + quad*8);

    f32x4 o[4] = {};
    float l_s = 0.f;

    const unsigned short* vrow = vtg + ((size_t)(b*H_ + h) * 64) * 2048;

    for (int kt = 0; kt < S_/128; ++kt){
        __syncthreads();
        #pragma unroll
        for (int c0 = 0; c0 < 2; ++c0){
            int c = tid + c0*512;                 // 1024 chunks each
            int rr = c >> 3, ch = c & 7;
            int sw = (ch ^ rr) & 7;
            gload_lds16(qkv + (base + kt*128 + rr)*2304 + D_ + hoff + sw*8, Kl + c*8);
            int d = c >> 4, pch = c & 15;
            int lch = (pch ^ d) & 15;
            gload_lds16(vrow + (size_t)d*2048 + kt*128 + lch*8, Vt + c*8);
        }
        __syncthreads();

        // mask fast-path flag (wave-uniform)
        int mv0 = mask[b*S_ + kt*128 + lane];
        int mv1 = mask[b*S_ + kt*128 + 64 + lane];
        const bool allok = __all((mv0 != 0) && (mv1 != 0));

        // 4 independent 32-key granules: S^T (2 tiles) -> exp2 -> pack -> PV
        #pragma unroll
        for (int t = 0; t < 4; ++t){
            f32x4 sf2[2] = {};
            #pragma unroll
            for (int kc = 0; kc < 2; ++kc){
                int co = (((kc*4 + quad) ^ l16) & 7)*8;
                short8 k0 = *(const short8*)&Kl[((2*t  )*16 + l16)*64 + co];
                short8 k1 = *(const short8*)&Kl[((2*t+1)*16 + l16)*64 + co];
                sf2[0] = __builtin_amdgcn_mfma_f32_16x16x32_bf16(k0, qf[kc], sf2[0], 0, 0, 0);
                sf2[1] = __builtin_amdgcn_mfma_f32_16x16x32_bf16(k1, qf[kc], sf2[1], 0, 0, 0);
            }
            if (!allok){
                #pragma unroll
                for (int j = 0; j < 2; ++j)
                    #pragma unroll
                    for (int r = 0; r < 4; ++r)
                        if (mask[b*S_ + kt*128 + (2*t+j)*16 + quad*4 + r] == 0)
                            sf2[j][r] = -1e30f;
            }
            #pragma unroll
            for (int j = 0; j < 2; ++j)
                #pragma unroll
                for (int r = 0; r < 4; ++r){
                    float p = __builtin_amdgcn_exp2f(sf2[j][r]);
                    sf2[j][r] = p; l_s += p;
                }
            union { unsigned int u[4]; short8 s; } pk;
            pk.u[0] = __builtin_amdgcn_perm(__float_as_uint(sf2[0][1]), __float_as_uint(sf2[0][0]), 0x07060302u);
            pk.u[1] = __builtin_amdgcn_perm(__float_as_uint(sf2[0][3]), __float_as_uint(sf2[0][2]), 0x07060302u);
            pk.u[2] = __builtin_amdgcn_perm(__float_as_uint(sf2[1][1]), __float_as_uint(sf2[1][0]), 0x07060302u);
            pk.u[3] = __builtin_amdgcn_perm(__float_as_uint(sf2[1][3]), __float_as_uint(sf2[1][2]), 0x07060302u);
            #pragma unroll
            for (int nt = 0; nt < 4; ++nt){
                int d = nt*16 + l16;
                short8 vf = *(const short8*)&Vt[d*128 + (((t*4 + quad) ^ l16) & 15)*8];
                o[nt] = __builtin_amdgcn_mfma_f32_16x16x32_bf16(pk.s, vf, o[nt], 0, 0, 0);
            }
        }
    }

    // reduce l across the 4 quad-copies of each column
    l_s += __shfl_xor(l_s, 16);
    l_s += __shfl_xor(l_s, 32);
    float linv[4];
    #pragma unroll
    for (int r = 0; r < 4; ++r)
        linv[r] = 1.f / __shfl(l_s, quad*4 + r);

    // repack ctx tile (16 q x 64 d per wave) through LDS for 16B coalesced stores
    __syncthreads();   // everyone done reading Kl
    #pragma unroll
    for (int nt = 0; nt < 4; ++nt)
        #pragma unroll
        for (int r = 0; r < 4; ++r)
            Kl[w*1024 + (quad*4 + r)*64 + nt*16 + l16] = f2b(o[nt][r] * linv[r]);
    asm volatile("s_waitcnt lgkmcnt(0)" ::: "memory");   // wave-local RAW
    #pragma unroll
    for (int c0 = 0; c0 < 2; ++c0){
        int c = lane + c0*64;
        int qrow = c >> 3, ch = c & 7;
        int4v vv = *(const int4v*)&Kl[w*1024 + qrow*64 + ch*8];
        *(int4v*)(ctx + (base + q0 + qrow)*D_ + hoff + ch*8) = vv;
    }
}

// ---------------------------------------------------------------- LayerNorm (+residual f32 or bf16, up to 2 partials)
__global__ __launch_bounds__(256) void ln_kernel(
    const float* __restrict__ inp, const float* __restrict__ inp2,
    const float* __restrict__ resf, const unsigned short* __restrict__ resb,
    const float* __restrict__ g, const float* __restrict__ be,
    float* __restrict__ outf, unsigned short* __restrict__ outb)
{
    const int row = blockIdx.x;
    const int tid = threadIdx.x;
    const float* ip = inp + (size_t)row * D_;
    const float* ip2 = inp2 ? inp2 + (size_t)row * D_ : nullptr;

    float v[3], s = 0.f, ss = 0.f;
    #pragma unroll
    for (int i = 0; i < 3; ++i){
        int c = tid + i*256;
        float x = ip[c];
        if (ip2) x += ip2[c];
        x += resf ? resf[(size_t)row * D_ + c] : b2f(resb[(size_t)row * D_ + c]);
        v[i] = x; s += x; ss += x * x;
    }
    #pragma unroll
    for (int d = 1; d < 64; d <<= 1){ s += __shfl_xor(s, d); ss += __shfl_xor(ss, d); }
    __shared__ float rs[4], rss[4];
    int w = tid >> 6;
    if ((tid & 63) == 0){ rs[w] = s; rss[w] = ss; }
    __syncthreads();
    s  = rs[0] + rs[1] + rs[2] + rs[3];
    ss = rss[0] + rss[1] + rss[2] + rss[3];
    float mu   = s * (1.f / 768.f);
    float var  = ss * (1.f / 768.f) - mu * mu;
    float rstd = rsqrtf(var + 1e-6f);
    #pragma unroll
    for (int i = 0; i < 3; ++i){
        int c = tid + i*256;
        float y = (v[i] - mu) * rstd * g[c] + be[c];
        if (outf) outf[(size_t)row * D_ + c] = y;
        if (outb) outb[(size_t)row * D_ + c] = f2b(y);
    }
}

// ---------------------------------------------------------------- launch
extern "C" void kernel_launch(void* const* d_in, const int* in_sizes, int n_in,
                              void* d_out, int out_size, void* d_ws, size_t ws_size,
                              hipStream_t stream)
{
    const float* x    = (const float*)d_in[0];
    const int*   mask = (const int*)  d_in[1];
    const float* Wq   = (const float*)d_in[2];
    const float* bq   = (const float*)d_in[3];
    const float* Wk   = (const float*)d_in[4];
    const float* bk   = (const float*)d_in[5];
    const float* Wv   = (const float*)d_in[6];
    const float* bv   = (const float*)d_in[7];
    const float* Wo   = (const float*)d_in[8];
    const float* bo   = (const float*)d_in[9];
    const float* W1   = (const float*)d_in[10];
    const float* b1   = (const float*)d_in[11];
    const float* W2   = (const float*)d_in[12];
    const float* b2   = (const float*)d_in[13];
    const float* g1   = (const float*)d_in[14];
    const float* be1  = (const float*)d_in[15];
    const float* g2   = (const float*)d_in[16];
    const float* be2  = (const float*)d_in[17];
    float* out = (float*)d_out;
    (void)in_sizes; (void)n_in; (void)out_size; (void)ws_size;

    char* ws = (char*)d_ws;
    const size_t n_x = (size_t)BS_ * D_;

    size_t off = 0;
    auto take = [&](size_t bytes){ size_t o = off; off += (bytes + 255) & ~(size_t)255; return o; };
    unsigned short* xb    = (unsigned short*)(ws + take(n_x * 2));   // dead after QKV; reused as hb
    unsigned short* hb    = xb;
    unsigned short* wqkvT = (unsigned short*)(ws + take((size_t)3*D_*D_ * 2));
    unsigned short* woT   = (unsigned short*)(ws + take((size_t)D_*D_ * 2));
    unsigned short* w1T   = (unsigned short*)(ws + take((size_t)D_*DF_ * 2));
    unsigned short* w2T   = (unsigned short*)(ws + take((size_t)D_*DF_ * 2));
    float*          bqkv  = (float*)(ws + take((size_t)3*D_ * 4));
    // qkv [BS][2304] + ctx [BS][768]; region reused by ff1 [BS][3072]
    size_t big = take((size_t)BS_ * 2304 * 2 + n_x * 2);
    unsigned short* qkvb = (unsigned short*)(ws + big);
    unsigned short* ctxb = qkvb + (size_t)BS_ * 2304;
    unsigned short* ff1b = qkvb;
    // fp32 partials (2x): Wo split-K partials, later FFN2 split-K partials
    float* pf32 = (float*)(ws + take(2 * n_x * 4));
    float* mhaf = pf32;
    float* ff2f = pf32;
    unsigned short* vtg = (unsigned short*)(ws + take(n_x * 2));   // [B*H][64][2048] bf16 (pi-permuted)

    // merged prep: cvt x (vec4) + 6 weight transposes + bias concat in ONE launch
    prep_kernel<<<6144 + 3*2304 + 9, 256, 0, stream>>>(
        x, Wq, Wk, Wv, Wo, W1, W2, bq, bk, bv,
        xb, wqkvT, woT, w1T, w2T, bqkv);

    dim3 blk(256);
    // fused QKV projection: Q scaled, K normal -> qkvb; V -> vtg transposed+permuted
    gemm_tn<<<dim3(18, 64, 1), blk, 0, stream>>>(xb, wqkvT, bqkv, nullptr, qkvb, vtg, BS_, 3*D_, D_, D_, 2);
    // attention (512-thread blocks)
    attn_kernel<<<B_ * H_ * (S_/128), 512, 0, stream>>>(qkvb, vtg, mask, ctxb);
    // output projection -> fp32, split-K=2
    gemm_tn<<<dim3(6, 64, 2), blk, 0, stream>>>(ctxb, woT, bo, mhaf, nullptr, nullptr, BS_, D_, D_, D_/2, 0);
    // LN1 (two Wo partials + residual x) -> h bf16 only
    ln_kernel<<<BS_, blk, 0, stream>>>(mhaf, mhaf + n_x, x, nullptr, g1, be1, nullptr, hb);
    // FFN1 + tanh-GELU -> bf16
    gemm_tn<<<dim3(24, 64, 1), blk, 0, stream>>>(hb, w1T, b1, nullptr, ff1b, nullptr, BS_, DF_, D_, D_, 1);
    // FFN2 -> fp32, split-K=2
    gemm_tn<<<dim3(6, 64, 2), blk, 0, stream>>>(ff1b, w2T, b2, ff2f, nullptr, nullptr, BS_, D_, DF_, DF_/2, 0);
    // LN2 -> out (two partials + bf16 residual h)
    ln_kernel<<<BS_, blk, 0, stream>>>(ff2f, ff2f + n_x, nullptr, hb, g2, be2, out, nullptr);
}

// Round 7
// 423.521 us; speedup vs baseline: 1.0355x; 1.0355x over previous
//
#include <hip/hip_runtime.h>
#include <hip/hip_bf16.h>
#include <math.h>

#define B_  4
#define S_  2048
#define D_  768
#define H_  12
#define HD_ 64
#define DF_ 3072
#define BS_ (B_*S_)

// 0.125 (hd^-0.5) * log2(e): folded into Q projection so softmax runs in exp2 domain
#define QSCALE 0.18033688011112042f

typedef __attribute__((ext_vector_type(8))) short short8;
typedef __attribute__((ext_vector_type(4))) float f32x4;
typedef __attribute__((ext_vector_type(4))) int  int4v;

__device__ __forceinline__ unsigned short f2b(float f){
    unsigned int x = __float_as_uint(f);
    return (unsigned short)((x + 0x7fffu + ((x >> 16) & 1u)) >> 16);   // RNE
}
__device__ __forceinline__ float b2f(unsigned short u){
    return __uint_as_float(((unsigned int)u) << 16);
}

typedef __attribute__((address_space(1))) void gvoid_t;
typedef __attribute__((address_space(3))) void lvoid_t;
__device__ __forceinline__ void gload_lds16(const unsigned short* g, unsigned short* l){
    __builtin_amdgcn_global_load_lds((gvoid_t*)g, (lvoid_t*)l, 16, 0, 0);
}

// ---------------------------------------------------------------- merged prep
// sections: 6144 cvt-x (float4) | 4*576 DxD transposes | 2304 W1 | 2304 W2 | 9 bias
__global__ __launch_bounds__(256) void prep_kernel(
    const float* __restrict__ x,
    const float* __restrict__ Wq, const float* __restrict__ Wk,
    const float* __restrict__ Wv, const float* __restrict__ Wo,
    const float* __restrict__ W1, const float* __restrict__ W2,
    const float* __restrict__ bq, const float* __restrict__ bk, const float* __restrict__ bv,
    unsigned short* __restrict__ xb, unsigned short* __restrict__ wqkvT,
    unsigned short* __restrict__ woT, unsigned short* __restrict__ w1T,
    unsigned short* __restrict__ w2T, float* __restrict__ bqkv)
{
    const int NCVT = (BS_*D_)/1024;        // 6144
    int bid = blockIdx.x;
    if (bid < NCVT){
        int i = (bid*256 + threadIdx.x)*4;
        float4 v = *(const float4*)(x + i);
        ushort4 o4 = { f2b(v.x), f2b(v.y), f2b(v.z), f2b(v.w) };
        *(ushort4*)(xb + i) = o4;
        return;
    }
    bid -= NCVT;
    __shared__ float t[32][33];
    const float* src; unsigned short* dst; int K, N, bx, by;
    if (bid < 4*576){
        int wsel = bid / 576, tt = bid % 576;
        bx = tt % 24; by = tt / 24; K = D_; N = D_;
        src = (wsel==0)?Wq:(wsel==1)?Wk:(wsel==2)?Wv:Wo;
        dst = (wsel<3) ? (wqkvT + (size_t)wsel*D_*D_) : woT;
    } else if (bid < 4*576 + 2304){
        int tt = bid - 4*576; bx = tt % 96; by = tt / 96; K = D_; N = DF_; src = W1; dst = w1T;
    } else if (bid < 4*576 + 2*2304){
        int tt = bid - 4*576 - 2304; bx = tt % 24; by = tt / 24; K = DF_; N = D_; src = W2; dst = w2T;
    } else {
        int i = (bid - (4*576 + 2*2304))*256 + threadIdx.x;
        if (i < 3*D_) bqkv[i] = (i < D_) ? bq[i] : (i < 2*D_) ? bk[i-D_] : bv[i-2*D_];
        return;
    }
    int tx = threadIdx.x & 31, ty = threadIdx.x >> 5;
    #pragma unroll
    for (int i = 0; i < 4; ++i)
        t[ty + i*8][tx] = src[(size_t)(by*32 + ty + i*8) * N + bx*32 + tx];
    __syncthreads();
    #pragma unroll
    for (int i = 0; i < 4; ++i)
        dst[(size_t)(bx*32 + ty + i*8) * K + by*32 + tx] = f2b(t[tx][ty + i*8]);
}

// ---------------------------------------------------------------- GEMM (R5 version: BK=64, 16x16x32)
// C[M,N] = A[M,K] @ Bt[N,K]^T + bias.  BM=BN=128, 4 waves 2x2 of 64x64.
// Staging via global_load_lds w/ XOR chunk swizzle (conflict-free frag reads).
// act: 0 none, 1 tanh-GELU, 2 QKV-mode. split-K via blockIdx.z (klen per z).
__global__ __launch_bounds__(256, 3) void gemm_tn(
    const unsigned short* __restrict__ A,
    const unsigned short* __restrict__ Bt,
    const float* __restrict__ bias,
    float* __restrict__ Cf,
    unsigned short* __restrict__ Cb,
    unsigned short* __restrict__ vtg,
    int M, int N, int K, int klen, int act)
{
    __shared__ __align__(16) unsigned short As[128*64];
    __shared__ __align__(16) unsigned short Bs[128*64];

    const int tid  = threadIdx.x;
    const int bm   = blockIdx.y, bn = blockIdx.x, bz = blockIdx.z;
    const int w    = tid >> 6, lane = tid & 63;
    const int l16  = lane & 15, quad = lane >> 4;
    const int wm   = (w >> 1) * 64, wn = (w & 1) * 64;
    const int kbeg = bz * klen;

    const unsigned short* Abase = A  + (size_t)bm * 128 * K;
    const unsigned short* Bbase = Bt + (size_t)bn * 128 * K;

    f32x4 acc[4][4] = {};

    for (int kt = kbeg; kt < kbeg + klen; kt += 64){
        #pragma unroll
        for (int c0 = 0; c0 < 4; ++c0){
            int c = tid + c0 * 256;                 // 1024 chunks of 16B per matrix
            int row = c >> 3, q = c & 7;
            int sw = (q ^ row) & 7;                 // chunk swizzle
            gload_lds16(Abase + (size_t)row * K + kt + sw*8, As + c*8);
            gload_lds16(Bbase + (size_t)row * K + kt + sw*8, Bs + c*8);
        }
        __syncthreads();

        #pragma unroll
        for (int kc = 0; kc < 2; ++kc){
            short8 af[4], bf[4];
            #pragma unroll
            for (int mi = 0; mi < 4; ++mi)
                af[mi] = *(const short8*)&As[(wm + mi*16 + l16)*64 + (((kc*4 + quad) ^ l16) & 7)*8];
            #pragma unroll
            for (int ni = 0; ni < 4; ++ni)
                bf[ni] = *(const short8*)&Bs[(wn + ni*16 + l16)*64 + (((kc*4 + quad) ^ l16) & 7)*8];
            #pragma unroll
            for (int mi = 0; mi < 4; ++mi)
                #pragma unroll
                for (int ni = 0; ni < 4; ++ni)
                    acc[mi][ni] = __builtin_amdgcn_mfma_f32_16x16x32_bf16(af[mi], bf[ni], acc[mi][ni], 0, 0, 0);
        }
        __syncthreads();
    }

    if (act == 2 && bn >= 12){
        // V cols: vtg[(b*H+h)*64 + d][s] with within-32 slot permutation
        // slot(k) = ((k>>2)&3)*8 + ((k>>4)&1)*4 + (k&3)
        #pragma unroll
        for (int mi = 0; mi < 4; ++mi){
            int rowbase = bm*128 + wm + mi*16 + quad*4;
            int bidx = rowbase >> 11, s0 = rowbase & 2047;
            int sp = (s0 & ~31) | (((s0 >> 2) & 3) << 3) | (((s0 >> 4) & 1) << 2);
            #pragma unroll
            for (int ni = 0; ni < 4; ++ni){
                int col  = bn*128 + wn + ni*16 + l16;
                int hcol = col - 2*D_;
                int hv   = hcol >> 6, dd = hcol & 63;
                float bia = bias ? bias[col] : 0.f;
                unsigned long long pk = 0;
                #pragma unroll
                for (int r = 0; r < 4; ++r)
                    pk |= (unsigned long long)f2b(acc[mi][ni][r] + bia) << (16*r);
                *(unsigned long long*)(vtg + (((size_t)bidx*H_ + hv)*64 + dd)*2048 + sp) = pk;
            }
        }
        return;
    }

    float* Cfz = Cf ? (Cf + (size_t)bz * M * N) : nullptr;
    const bool addb = (bias != nullptr) && (bz == 0);
    #pragma unroll
    for (int mi = 0; mi < 4; ++mi){
        #pragma unroll
        for (int ni = 0; ni < 4; ++ni){
            int col = bn*128 + wn + ni*16 + l16;
            float bia = addb ? bias[col] : 0.f;
            #pragma unroll
            for (int r = 0; r < 4; ++r){
                int row = bm*128 + wm + mi*16 + quad*4 + r;
                float v = acc[mi][ni][r] + bia;
                if (act == 1){
                    // tanh-GELU (max abs err ~3e-4, well within tolerance)
                    float u = v * (0.7978845608028654f + 0.0356774081f * v * v);
                    float e = __builtin_amdgcn_exp2f(u * 2.885390081777927f);  // e^(2u)
                    v = 0.5f * v * (1.f + (1.f - 2.f / (e + 1.f)));
                } else if (act == 2 && col < D_) v *= QSCALE;
                size_t idx = (size_t)row * N + col;
                if (Cfz) Cfz[idx] = v;
                if (Cb) Cb[idx] = f2b(v);
            }
        }
    }
}

// ---------------------------------------------------------------- attention (key-split waves)
// S^T = K Q^T; P^T's C-layout regs ARE the PV A-fragment under key-permutation pi;
// V^T stored globally with pi pre-applied. No-max softmax (p = exp2(s) directly).
// 512 threads: waves 0-3 = q-tiles x keys[0,64), waves 4-7 = same q x keys[64,128).
// Each wave: 32 q (2 q-tiles) -> every K/V fragment read feeds 2 MFMAs (halved
// LDS-read per MAC vs R5; attn was at ~65% of LDS BW). o/l combined via LDS once.
__global__ __launch_bounds__(512, 4) void attn_kernel(
    const unsigned short* __restrict__ qkv,
    const unsigned short* __restrict__ vtg,
    const int* __restrict__ mask,
    unsigned short* __restrict__ ctx)
{
    __shared__ __align__(16) unsigned short SMEM[128*64 + 64*128]; // Kl | Vt (32 KB)
    __shared__ float Ls[4][2][16];
    unsigned short* Kl = SMEM;            // [key][dchunk ^ (key&7)]
    unsigned short* Vt = SMEM + 128*64;   // [d][slotchunk ^ (d&15)]

    const int tid = threadIdx.x;
    const int bid = blockIdx.x;                  // 768 = 48 heads * 16 qb
    const int hid = bid % 48;                    // same head -> same XCD (bid%8 fixed)
    const int qb  = bid / 48;
    const int h   = hid % H_;
    const int b   = hid / H_;
    const int w   = tid >> 6, lane = tid & 63;
    const int l16 = lane & 15, quad = lane >> 4;
    const int wq  = w & 3;                       // q-wave index
    const int kh  = w >> 2;                      // key-half (0: keys 0-63, 1: 64-127)
    const int q0  = qb * 128 + wq * 32;
    const size_t base = (size_t)b * S_;
    const int hoff = h * HD_;

    // Q as B-frag: n=q=lane&15, k-slot (quad,j) -> d = kc*32+quad*8+j
    short8 qf[2][2];
    #pragma unroll
    for (int nq = 0; nq < 2; ++nq)
        #pragma unroll
        for (int kc = 0; kc < 2; ++kc)
            qf[nq][kc] = *(const short8*)(qkv + (base + q0 + nq*16 + l16)*2304 + hoff + kc*32 + quad*8);

    f32x4 o[2][4] = {};
    float l_s[2] = {0.f, 0.f};

    const unsigned short* vrow = vtg + ((size_t)(b*H_ + h) * 64) * 2048;

    for (int kt = 0; kt < S_/128; ++kt){
        __syncthreads();
        #pragma unroll
        for (int c0 = 0; c0 < 2; ++c0){
            int c = tid + c0*512;                 // 1024 chunks each
            int rr = c >> 3, ch = c & 7;
            int sw = (ch ^ rr) & 7;
            gload_lds16(qkv + (base + kt*128 + rr)*2304 + D_ + hoff + sw*8, Kl + c*8);
            int d = c >> 4, pch = c & 15;
            int lch = (pch ^ d) & 15;
            gload_lds16(vrow + (size_t)d*2048 + kt*128 + lch*8, Vt + c*8);
        }
        __syncthreads();

        // mask fast-path flag over this wave's 64 keys
        int mv = mask[b*S_ + kt*128 + kh*64 + lane];
        const bool allok = __all(mv != 0);

        // 2 granules of 32 keys: S^T (2 tiles x 2 q) -> exp2 -> pack -> PV
        #pragma unroll
        for (int t = 0; t < 2; ++t){
            const int tg = kh*2 + t;
            f32x4 sf[2][2] = {};
            #pragma unroll
            for (int kc = 0; kc < 2; ++kc){
                int co = (((kc*4 + quad) ^ l16) & 7)*8;
                short8 k0 = *(const short8*)&Kl[((2*tg  )*16 + l16)*64 + co];
                short8 k1 = *(const short8*)&Kl[((2*tg+1)*16 + l16)*64 + co];
                #pragma unroll
                for (int nq = 0; nq < 2; ++nq){
                    sf[nq][0] = __builtin_amdgcn_mfma_f32_16x16x32_bf16(k0, qf[nq][kc], sf[nq][0], 0, 0, 0);
                    sf[nq][1] = __builtin_amdgcn_mfma_f32_16x16x32_bf16(k1, qf[nq][kc], sf[nq][1], 0, 0, 0);
                }
            }
            if (!allok){
                #pragma unroll
                for (int j = 0; j < 2; ++j)
                    #pragma unroll
                    for (int r = 0; r < 4; ++r)
                        if (mask[b*S_ + kt*128 + (2*tg+j)*16 + quad*4 + r] == 0){
                            sf[0][j][r] = -1e30f; sf[1][j][r] = -1e30f;
                        }
            }
            #pragma unroll
            for (int nq = 0; nq < 2; ++nq)
                #pragma unroll
                for (int j = 0; j < 2; ++j)
                    #pragma unroll
                    for (int r = 0; r < 4; ++r){
                        float p = __builtin_amdgcn_exp2f(sf[nq][j][r]);
                        sf[nq][j][r] = p; l_s[nq] += p;
                    }
            short8 pf[2];
            #pragma unroll
            for (int nq = 0; nq < 2; ++nq){
                union { unsigned int u[4]; short8 s; } pk;
                pk.u[0] = __builtin_amdgcn_perm(__float_as_uint(sf[nq][0][1]), __float_as_uint(sf[nq][0][0]), 0x07060302u);
                pk.u[1] = __builtin_amdgcn_perm(__float_as_uint(sf[nq][0][3]), __float_as_uint(sf[nq][0][2]), 0x07060302u);
                pk.u[2] = __builtin_amdgcn_perm(__float_as_uint(sf[nq][1][1]), __float_as_uint(sf[nq][1][0]), 0x07060302u);
                pk.u[3] = __builtin_amdgcn_perm(__float_as_uint(sf[nq][1][3]), __float_as_uint(sf[nq][1][2]), 0x07060302u);
                pf[nq] = pk.s;
            }
            #pragma unroll
            for (int nt = 0; nt < 4; ++nt){
                int d = nt*16 + l16;
                short8 vf = *(const short8*)&Vt[d*128 + (((tg*4 + quad) ^ l16) & 15)*8];
                #pragma unroll
                for (int nq = 0; nq < 2; ++nq)
                    o[nq][nt] = __builtin_amdgcn_mfma_f32_16x16x32_bf16(pf[nq], vf, o[nq][nt], 0, 0, 0);
            }
        }
    }

    // reduce l over quad copies within wave (value per q = nq*16 + l16)
    #pragma unroll
    for (int nq = 0; nq < 2; ++nq){
        l_s[nq] += __shfl_xor(l_s[nq], 16);
        l_s[nq] += __shfl_xor(l_s[nq], 32);
    }

    // combine key-halves: waves 4-7 publish o/l, waves 0-3 accumulate
    float* Ol = (float*)SMEM;                       // 8192 floats = 32 KB
    __syncthreads();
    if (w >= 4){
        #pragma unroll
        for (int nq = 0; nq < 2; ++nq){
            #pragma unroll
            for (int nt = 0; nt < 4; ++nt)
                *(f32x4*)&Ol[(((w-4)*64 + lane)*32) + nq*16 + nt*4] = o[nq][nt];
            if (quad == 0) Ls[w-4][nq][l16] = l_s[nq];
        }
    }
    __syncthreads();
    if (w < 4){
        #pragma unroll
        for (int nq = 0; nq < 2; ++nq){
            #pragma unroll
            for (int nt = 0; nt < 4; ++nt)
                o[nq][nt] += *(const f32x4*)&Ol[((w*64 + lane)*32) + nq*16 + nt*4];
            l_s[nq] += Ls[w][nq][l16];
        }
    }
    __syncthreads();
    if (w < 4){
        // normalize + repack through LDS for 16B coalesced ctx stores
        #pragma unroll
        for (int nq = 0; nq < 2; ++nq){
            float linv[4];
            #pragma unroll
            for (int r = 0; r < 4; ++r)
                linv[r] = 1.f / __shfl(l_s[nq], quad*4 + r);
            #pragma unroll
            for (int nt = 0; nt < 4; ++nt)
                #pragma unroll
                for (int r = 0; r < 4; ++r)
                    SMEM[w*2048 + (nq*16 + quad*4 + r)*64 + nt*16 + l16] = f2b(o[nq][nt][r] * linv[r]);
        }
        asm volatile("s_waitcnt lgkmcnt(0)" ::: "memory");   // wave-local RAW
        #pragma unroll
        for (int c0 = 0; c0 < 4; ++c0){
            int c = lane + c0*64;
            int qrow = c >> 3, ch = c & 7;
            int4v vv = *(const int4v*)&SMEM[w*2048 + qrow*64 + ch*8];
            *(int4v*)(ctx + (base + q0 + qrow)*D_ + hoff + ch*8) = vv;
        }
    }
}

// ---------------------------------------------------------------- LayerNorm (+residual f32 or bf16, up to 2 partials)
__global__ __launch_bounds__(256) void ln_kernel(
    const float* __restrict__ inp, const float* __restrict__ inp2,
    const float* __restrict__ resf, const unsigned short* __restrict__ resb,
    const float* __restrict__ g, const float* __restrict__ be,
    float* __restrict__ outf, unsigned short* __restrict__ outb)
{
    const int row = blockIdx.x;
    const int tid = threadIdx.x;
    const float* ip = inp + (size_t)row * D_;
    const float* ip2 = inp2 ? inp2 + (size_t)row * D_ : nullptr;

    float v[3], s = 0.f, ss = 0.f;
    #pragma unroll
    for (int i = 0; i < 3; ++i){
        int c = tid + i*256;
        float x = ip[c];
        if (ip2) x += ip2[c];
        x += resf ? resf[(size_t)row * D_ + c] : b2f(resb[(size_t)row * D_ + c]);
        v[i] = x; s += x; ss += x * x;
    }
    #pragma unroll
    for (int d = 1; d < 64; d <<= 1){ s += __shfl_xor(s, d); ss += __shfl_xor(ss, d); }
    __shared__ float rs[4], rss[4];
    int w = tid >> 6;
    if ((tid & 63) == 0){ rs[w] = s; rss[w] = ss; }
    __syncthreads();
    s  = rs[0] + rs[1] + rs[2] + rs[3];
    ss = rss[0] + rss[1] + rss[2] + rss[3];
    float mu   = s * (1.f / 768.f);
    float var  = ss * (1.f / 768.f) - mu * mu;
    float rstd = rsqrtf(var + 1e-6f);
    #pragma unroll
    for (int i = 0; i < 3; ++i){
        int c = tid + i*256;
        float y = (v[i] - mu) * rstd * g[c] + be[c];
        if (outf) outf[(size_t)row * D_ + c] = y;
        if (outb) outb[(size_t)row * D_ + c] = f2b(y);
    }
}

// ---------------------------------------------------------------- launch
extern "C" void kernel_launch(void* const* d_in, const int* in_sizes, int n_in,
                              void* d_out, int out_size, void* d_ws, size_t ws_size,
                              hipStream_t stream)
{
    const float* x    = (const float*)d_in[0];
    const int*   mask = (const int*)  d_in[1];
    const float* Wq   = (const float*)d_in[2];
    const float* bq   = (const float*)d_in[3];
    const float* Wk   = (const float*)d_in[4];
    const float* bk   = (const float*)d_in[5];
    const float* Wv   = (const float*)d_in[6];
    const float* bv   = (const float*)d_in[7];
    const float* Wo   = (const float*)d_in[8];
    const float* bo   = (const float*)d_in[9];
    const float* W1   = (const float*)d_in[10];
    const float* b1   = (const float*)d_in[11];
    const float* W2   = (const float*)d_in[12];
    const float* b2   = (const float*)d_in[13];
    const float* g1   = (const float*)d_in[14];
    const float* be1  = (const float*)d_in[15];
    const float* g2   = (const float*)d_in[16];
    const float* be2  = (const float*)d_in[17];
    float* out = (float*)d_out;
    (void)in_sizes; (void)n_in; (void)out_size; (void)ws_size;

    char* ws = (char*)d_ws;
    const size_t n_x = (size_t)BS_ * D_;

    size_t off = 0;
    auto take = [&](size_t bytes){ size_t o = off; off += (bytes + 255) & ~(size_t)255; return o; };
    unsigned short* xb    = (unsigned short*)(ws + take(n_x * 2));   // dead after QKV; reused as hb
    unsigned short* hb    = xb;
    unsigned short* wqkvT = (unsigned short*)(ws + take((size_t)3*D_*D_ * 2));
    unsigned short* woT   = (unsigned short*)(ws + take((size_t)D_*D_ * 2));
    unsigned short* w1T   = (unsigned short*)(ws + take((size_t)D_*DF_ * 2));
    unsigned short* w2T   = (unsigned short*)(ws + take((size_t)D_*DF_ * 2));
    float*          bqkv  = (float*)(ws + take((size_t)3*D_ * 4));
    // qkv [BS][2304] + ctx [BS][768]; region reused by ff1 [BS][3072]
    size_t big = take((size_t)BS_ * 2304 * 2 + n_x * 2);
    unsigned short* qkvb = (unsigned short*)(ws + big);
    unsigned short* ctxb = qkvb + (size_t)BS_ * 2304;
    unsigned short* ff1b = qkvb;
    // fp32 partials (2x): Wo split-K partials, later FFN2 split-K partials
    float* pf32 = (float*)(ws + take(2 * n_x * 4));
    float* mhaf = pf32;
    float* ff2f = pf32;
    unsigned short* vtg = (unsigned short*)(ws + take(n_x * 2));   // [B*H][64][2048] bf16 (pi-permuted)

    // merged prep: cvt x (vec4) + 6 weight transposes + bias concat in ONE launch
    prep_kernel<<<6144 + 3*2304 + 9, 256, 0, stream>>>(
        x, Wq, Wk, Wv, Wo, W1, W2, bq, bk, bv,
        xb, wqkvT, woT, w1T, w2T, bqkv);

    dim3 blk(256);
    // fused QKV projection: Q scaled, K normal -> qkvb; V -> vtg transposed+permuted
    gemm_tn<<<dim3(18, 64, 1), blk, 0, stream>>>(xb, wqkvT, bqkv, nullptr, qkvb, vtg, BS_, 3*D_, D_, D_, 2);
    // attention (512-thread blocks, key-split waves)
    attn_kernel<<<B_ * H_ * (S_/128), 512, 0, stream>>>(qkvb, vtg, mask, ctxb);
    // output projection -> fp32, split-K=2
    gemm_tn<<<dim3(6, 64, 2), blk, 0, stream>>>(ctxb, woT, bo, mhaf, nullptr, nullptr, BS_, D_, D_, D_/2, 0);
    // LN1 (two Wo partials + residual x) -> h bf16 only
    ln_kernel<<<BS_, blk, 0, stream>>>(mhaf, mhaf + n_x, x, nullptr, g1, be1, nullptr, hb);
    // FFN1 + tanh-GELU -> bf16
    gemm_tn<<<dim3(24, 64, 1), blk, 0, stream>>>(hb, w1T, b1, nullptr, ff1b, nullptr, BS_, DF_, D_, D_, 1);
    // FFN2 -> fp32, split-K=2
    gemm_tn<<<dim3(6, 64, 2), blk, 0, stream>>>(ff1b, w2T, b2, ff2f, nullptr, nullptr, BS_, D_, DF_, DF_/2, 0);
    // LN2 -> out (two partials + bf16 residual h)
    ln_kernel<<<BS_, blk, 0, stream>>>(ff2f, ff2f + n_x, nullptr, hb, g2, be2, out, nullptr);
}